// Round 15
// baseline (1677.338 us; speedup 1.0000x reference)
//
#include <hip/hip_runtime.h>

// ---------------------------------------------------------------------------
// RatingLayer: 2-round fully-connected 2-node GRU + linear head.
// One [24576,4096]^T bf16 GEMM per round. Round 15 = r7 (best: 4-phase
// read-ahead, counted vmcnt) with MFMA switched 16x16x32 -> 32x32x16
// (measured ceiling 2495 vs 2176 TF, -17% matrix-pipe cycles; identical LDS
// traffic, acc size, stage ledger, gates). r14's 3-phase merge reverted.
// Frag map: a_hi=m-tiles{2,3} in G1/G3, a_lo=m-tiles{0,1} in G0/G2 (same
// granules as r7's a47/a03); b0/b1 = n-tile halves of the wave's B granule.
// C/D layout (m74/m101): col=lane&31, row=(reg&3)+8*(reg>>2)+4*(lane>>5).
// ---------------------------------------------------------------------------

typedef __bf16 bf16x8 __attribute__((ext_vector_type(8)));
typedef float  f32x4  __attribute__((ext_vector_type(4)));
typedef float  f32x16 __attribute__((ext_vector_type(16)));
typedef unsigned short u16x4 __attribute__((ext_vector_type(4)));

#define HH    4096
#define NI_D  2048
#define N3H   12288
#define N6H   24576
#define BSZ   4096
#define BM    256
#define BN    256
#define BK    64
#define MT    (BSZ / BM)     // 16
#define NT    (N6H / BN)     // 96
#define GRID_GEMM (MT * NT)  // 1536
#define NKT   (HH / BK)      // 64 K-tiles

#define NB_W  98304
#define NB_C  16384

__device__ __forceinline__ unsigned short f2bf(float f) {
  unsigned u = __float_as_uint(f);
  u += 0x7FFFu + ((u >> 16) & 1u);
  return (unsigned short)(u >> 16);
}
__device__ __forceinline__ float bf2f(unsigned short s) {
  return __uint_as_float(((unsigned)s) << 16);
}

__device__ __forceinline__ void gload16(const void* g, void* l) {
  void* gv = (void*)g;
  __builtin_amdgcn_global_load_lds(
      (__attribute__((address_space(1))) unsigned int*)gv,
      (__attribute__((address_space(3))) unsigned int*)l,
      16, 0, 0);
}

// --- fused prep: Wc[j][k] = bf16(j<3H ? W_ih[j][(k+NI)%H] : W_hh[j-3H][k]);
//     hb = bf16(features)
__global__ void __launch_bounds__(256)
prep(const float* __restrict__ Wih, const float* __restrict__ Whh,
     const float* __restrict__ feat,
     unsigned short* __restrict__ Wc, unsigned short* __restrict__ hb)
{
  int bid = blockIdx.x;
  if (bid < NB_W) {
    int idx = (bid * 256 + threadIdx.x) << 2;
    int j = idx >> 12;
    int k = idx & 4095;
    const float* src;
    if (j < N3H) src = Wih + (size_t)j * HH + ((k + NI_D) & (HH - 1));
    else         src = Whh + (size_t)(j - N3H) * HH + k;
    f32x4 v = *(const f32x4*)src;
    u16x4 o = { f2bf(v[0]), f2bf(v[1]), f2bf(v[2]), f2bf(v[3]) };
    *(u16x4*)(Wc + idx) = o;
  } else {
    int i = ((bid - NB_W) * 256 + threadIdx.x) << 2;
    f32x4 v = *(const f32x4*)(feat + i);
    u16x4 o = { f2bf(v[0]), f2bf(v[1]), f2bf(v[2]), f2bf(v[3]) };
    *(u16x4*)(hb + i) = o;
  }
}

// ---------------------------------------------------------------------------
// GEMM helpers. LDS: A buf d at d*32768 (256 rows x 128 B), B buf d at
// 65536 + d*32768. Granule g = 64 rows = one gload16/thread (8 KB). Linear
// LDS dest; global source column pre-swizzled by ((row&7)<<4) (rule 21).
// ---------------------------------------------------------------------------
__device__ __forceinline__ void stageA(const char* a_base, char* lds, int ldst,
                                       int d, int kt, int g) {
  int kc = (kt < NKT) ? kt : 0;                 // dummy tail loads, race-safe
  gload16(a_base + (size_t)kc * 128 + (size_t)g * 524288,
          lds + d * 32768 + g * 8192 + ldst);
}
__device__ __forceinline__ void stageB(const char* b_base, char* lds, int ldst,
                                       int d, int kt, int g) {
  int kc = (kt < NKT) ? kt : 0;
  gload16(b_base + (size_t)kc * 128 + (size_t)g * 524288,
          lds + 65536 + d * 32768 + g * 8192 + ldst);
}

// 8 MFMAs (32x32x16): tiles (MB,NT),(MB+1,NT) over 4 k-steps.
template <int MB, int NTI>
__device__ __forceinline__ void mfma8(f32x16 (&acc)[4][2],
                                      const bf16x8 (&a)[2][4],
                                      const bf16x8 (&b)[4]) {
  __builtin_amdgcn_s_setprio(1);
#pragma unroll
  for (int ks = 0; ks < 4; ++ks)
#pragma unroll
    for (int m = 0; m < 2; ++m)
      acc[MB + m][NTI] = __builtin_amdgcn_mfma_f32_32x32x16_bf16(
          a[m][ks], b[ks], acc[MB + m][NTI], 0, 0, 0);
  __builtin_amdgcn_s_setprio(0);
}

#define BAR   __builtin_amdgcn_s_barrier()
#define SB    __builtin_amdgcn_sched_barrier(0)
#define LGKM0 do { asm volatile("s_waitcnt lgkmcnt(0)" ::: "memory"); SB; } while (0)
#define VM6   asm volatile("s_waitcnt vmcnt(6)" ::: "memory")

// One K-tile, r7 read-ahead schedule (ledger/gates unchanged). Entry:
// ahiC (m-tiles 2,3) + b0C (n-tile 0) read during prev tile's ph3, landed
// via ph0's LGKM0. ph3 fills ahiN/b0N from buffer D^1.
// Stage ledger per wave (steady state):
//   ph0: A(t1)G0,G2 -> D^1 | ph1: A(t2)G1,G3 -> D | ph2: B(t2)G0,G1 -> D
//   ph3: B(t2)G2,G3 -> D
// Gates: ph0 VM6 retires (t-1)ph1-and-older -> a_lo(t) staging landed.
//        ph2 VM6 retires (t-1)ph3-and-older -> D^1 fully valid for ph3 reads.
template <int D>
__device__ __forceinline__ void kblock(char* lds, const char* a_base,
                                       const char* b_base, int ldst,
                                       int aro, int bro, const int (&ok)[4],
                                       int t1, int t2, f32x16 (&acc)[4][2],
                                       bf16x8 (&ahiC)[2][4], bf16x8 (&b0C)[4],
                                       bf16x8 (&ahiN)[2][4], bf16x8 (&b0N)[4]) {
  const char* LA  = lds + D * 32768 + aro;
  const char* LB  = lds + 65536 + D * 32768 + bro;
  const char* LAn = lds + (D ^ 1) * 32768 + aro;
  const char* LBn = lds + 65536 + (D ^ 1) * 32768 + bro;
  bf16x8 alo[2][4], b1[4];

  // ---- ph0: MFMA(ahi x n0) 8; read-ahead b1; stage A(t1)G0,G2 -> D^1.
  LGKM0;                                 // ahiC,b0C landed
#pragma unroll
  for (int ks = 0; ks < 4; ++ks)
    b1[ks] = *(const bf16x8*)(LB + 4096 + ok[ks]);
  stageA(a_base, lds, ldst, D ^ 1, t1, 0);
  stageA(a_base, lds, ldst, D ^ 1, t1, 2);
  SB;
  mfma8<2, 0>(acc, ahiC, b0C);
  VM6;
  BAR;

  // ---- ph1: MFMA(ahi x n1) 8; read-ahead alo; stage A(t2)G1,G3 -> D.
  LGKM0;                                 // b1 landed (flew under ph0 MFMA)
#pragma unroll
  for (int m = 0; m < 2; ++m)
#pragma unroll
    for (int ks = 0; ks < 4; ++ks)
      alo[m][ks] = *(const bf16x8*)(LA + m * 4096 + ok[ks]);
  stageA(a_base, lds, ldst, D, t2, 1);
  stageA(a_base, lds, ldst, D, t2, 3);
  SB;
  mfma8<2, 1>(acc, ahiC, b1);
  BAR;

  // ---- ph2: MFMA(alo x n0) 8; stage B(t2)G0,G1 -> D; gate D^1 validity.
  LGKM0;                                 // alo landed
  stageB(b_base, lds, ldst, D, t2, 0);
  stageB(b_base, lds, ldst, D, t2, 1);
  SB;
  mfma8<0, 0>(acc, alo, b0C);
  VM6;
  BAR;

  // ---- ph3: MFMA(alo x n1) 8; read next tile's ahi,b0 from D^1;
  //           stage B(t2)G2,G3 -> D.
#pragma unroll
  for (int m = 0; m < 2; ++m)
#pragma unroll
    for (int ks = 0; ks < 4; ++ks)
      ahiN[m][ks] = *(const bf16x8*)(LAn + (2 + m) * 4096 + ok[ks]);
#pragma unroll
  for (int ks = 0; ks < 4; ++ks)
    b0N[ks] = *(const bf16x8*)(LBn + ok[ks]);
  stageB(b_base, lds, ldst, D, t2, 2);
  stageB(b_base, lds, ldst, D, t2, 3);
  SB;
  mfma8<0, 1>(acc, alo, b1);
  BAR;
}

// ---------------------------------------------------------------------------
// C[4096, 24576] bf16 = A[4096,4096] * B[24576,4096]^T   (bf16 in, bf16 out)
// 256x256 tile, BK=64, 512 threads (8 waves, 2Mx4N), LDS 128 KB (2 dbuf).
// Per wave: 4x2 tiles of 32x32, MFMA 32x32x16.
// ---------------------------------------------------------------------------
__global__ void __launch_bounds__(512, 2)
gemm_bt(const unsigned short* __restrict__ A,
        const unsigned short* __restrict__ B,
        unsigned short* __restrict__ C)
{
  __shared__ alignas(16) char lds[131072];

  int bid = blockIdx.x;
  int wg  = (bid & 7) * (GRID_GEMM / 8) + (bid >> 3);  // XCD swizzle, 1536%8==0
  int nt  = wg / MT;          // n-major: 16 consecutive wg share one W panel
  int mt  = wg % MT;
  int m0  = mt * BM;
  int n0  = nt * BN;

  int t  = threadIdx.x;
  int wv = t >> 6;
  int l  = t & 63;
  int wm = wv >> 2;
  int wn = wv & 3;

  // staging: thread covers row rloc of a 64-row granule, 16B chunk (l&7),
  // source column XOR-preswizzled by row&7 = l>>3.
  int rloc   = wv * 8 + (l >> 3);
  int sg_col = ((l & 7) ^ (l >> 3)) << 4;
  const char* a_base = (const char*)A + (size_t)(m0 + rloc) * 8192 + sg_col;
  const char* b_base = (const char*)B + (size_t)(n0 + rloc) * 8192 + sg_col;
  int ldst = wv * 1024;       // wave-uniform LDS dest offset within granule

  // read-side: row = (l&31); k-step ks -> byte (ks*32 + (l>>5)*16), swizzled.
  int swz = (l & 7) << 4;
  int kb  = (l >> 5) << 4;
  const int ok[4] = { (0 + kb) ^ swz, (32 + kb) ^ swz,
                      (64 + kb) ^ swz, (96 + kb) ^ swz };
  int aro = (wm * 128 + (l & 31)) * 128;
  int bro = (wn * 64  + (l & 31)) * 128;

  f32x16 acc[4][2] = {};
  bf16x8 ahiA[2][4], b0A[4], ahiB[2][4], b0B[4];

  // prologue (r7): D0 complete (8 loads), then steady in-flight set
  // {A(1)G1,G3, B(1)G0-3} (6). vmcnt(6) -> D0 landed. Read tile0's entry
  // frags (ahiA,b0A) from D0; ph0's LGKM0 gates them.
#pragma unroll
  for (int g = 0; g < 4; ++g) stageA(a_base, lds, ldst, 0, 0, g);
#pragma unroll
  for (int g = 0; g < 4; ++g) stageB(b_base, lds, ldst, 0, 0, g);
  stageA(a_base, lds, ldst, 1, 1, 1);
  stageA(a_base, lds, ldst, 1, 1, 3);
#pragma unroll
  for (int g = 0; g < 4; ++g) stageB(b_base, lds, ldst, 1, 1, g);
  asm volatile("s_waitcnt vmcnt(6)" ::: "memory");
  BAR;
  {
    const char* LA0 = lds + aro;
    const char* LB0 = lds + 65536 + bro;
#pragma unroll
    for (int m = 0; m < 2; ++m)
#pragma unroll
      for (int ks = 0; ks < 4; ++ks)
        ahiA[m][ks] = *(const bf16x8*)(LA0 + (2 + m) * 4096 + ok[ks]);
#pragma unroll
    for (int ks = 0; ks < 4; ++ks)
      b0A[ks] = *(const bf16x8*)(LB0 + ok[ks]);
  }

#pragma unroll 1
  for (int tt = 0; tt < NKT; tt += 2) {
    kblock<0>(lds, a_base, b_base, ldst, aro, bro, ok,
              tt + 1, tt + 2, acc, ahiA, b0A, ahiB, b0B);
    kblock<1>(lds, a_base, b_base, ldst, aro, bro, ok,
              tt + 2, tt + 3, acc, ahiB, b0B, ahiA, b0A);
  }
  asm volatile("s_waitcnt vmcnt(0) lgkmcnt(0)" ::: "memory");  // drain tails

  // C-write: 32x32 frag layout (m74/m101): col = lane&31,
  // row = (reg&3) + 8*(reg>>2) + 4*(lane>>5).
  int crow0 = m0 + wm * 128 + ((l >> 5) << 2);
  int ccol  = n0 + wn * 64 + (l & 31);
#pragma unroll
  for (int mti = 0; mti < 4; ++mti)
#pragma unroll
    for (int nti = 0; nti < 2; ++nti)
#pragma unroll
      for (int r = 0; r < 16; ++r) {
        int row = crow0 + mti * 32 + (r & 3) + ((r >> 2) << 3);
        C[(size_t)row * N6H + (ccol + nti * 32)] = f2bf(acc[mti][nti][r]);
      }
}

// --- round-1 GRU: h_old = features (f32); writes h1 as bf16 only.
__global__ void __launch_bounds__(256)
gru1(const unsigned short* __restrict__ C, const float* __restrict__ h_old,
     const float* __restrict__ b_ih, const float* __restrict__ b_hh,
     unsigned short* __restrict__ h_bf)
{
  int idx = blockIdx.x * 256 + threadIdx.x;
  int b = idx >> 10;
  int j = (idx & 1023) << 2;
  const unsigned short* Cr = C + (size_t)b * N6H;
  u16x4 gir = *(const u16x4*)(Cr + j);
  u16x4 giz = *(const u16x4*)(Cr + HH + j);
  u16x4 gin = *(const u16x4*)(Cr + 2 * HH + j);
  u16x4 ghr = *(const u16x4*)(Cr + 3 * HH + j);
  u16x4 ghz = *(const u16x4*)(Cr + 4 * HH + j);
  u16x4 ghn = *(const u16x4*)(Cr + 5 * HH + j);
  f32x4 bir = *(const f32x4*)(b_ih + j);
  f32x4 biz = *(const f32x4*)(b_ih + HH + j);
  f32x4 bin = *(const f32x4*)(b_ih + 2 * HH + j);
  f32x4 bhr = *(const f32x4*)(b_hh + j);
  f32x4 bhz = *(const f32x4*)(b_hh + HH + j);
  f32x4 bhn = *(const f32x4*)(b_hh + 2 * HH + j);
  f32x4 ho  = *(const f32x4*)(h_old + (size_t)b * HH + j);
  u16x4 hb;
#pragma unroll
  for (int e = 0; e < 4; ++e) {
    float r = 1.f / (1.f + expf(-(bf2f(gir[e]) + bir[e] + bf2f(ghr[e]) + bhr[e])));
    float z = 1.f / (1.f + expf(-(bf2f(giz[e]) + biz[e] + bf2f(ghz[e]) + bhz[e])));
    float n = tanhf(bf2f(gin[e]) + bin[e] + r * (bf2f(ghn[e]) + bhn[e]));
    hb[e] = f2bf((1.f - z) * n + z * ho[e]);
  }
  *(u16x4*)(h_bf + (size_t)b * HH + j) = hb;
}

// --- round-2 GRU fused with FC head: h_old = h1 (bf16); per-block partial
// dot(h2, fc_w) -> atomicAdd(out[b]). out zeroed by memset each call.
__global__ void __launch_bounds__(256)
gru2_fc(const unsigned short* __restrict__ C,
        const unsigned short* __restrict__ h_old_bf,
        const float* __restrict__ b_ih, const float* __restrict__ b_hh,
        const float* __restrict__ fcw, const float* __restrict__ fcb,
        float* __restrict__ out)
{
  int idx = blockIdx.x * 256 + threadIdx.x;
  int b = idx >> 10;
  int j = (idx & 1023) << 2;
  const unsigned short* Cr = C + (size_t)b * N6H;
  u16x4 gir = *(const u16x4*)(Cr + j);
  u16x4 giz = *(const u16x4*)(Cr + HH + j);
  u16x4 gin = *(const u16x4*)(Cr + 2 * HH + j);
  u16x4 ghr = *(const u16x4*)(Cr + 3 * HH + j);
  u16x4 ghz = *(const u16x4*)(Cr + 4 * HH + j);
  u16x4 ghn = *(const u16x4*)(Cr + 5 * HH + j);
  f32x4 bir = *(const f32x4*)(b_ih + j);
  f32x4 biz = *(const f32x4*)(b_ih + HH + j);
  f32x4 bin = *(const f32x4*)(b_ih + 2 * HH + j);
  f32x4 bhr = *(const f32x4*)(b_hh + j);
  f32x4 bhz = *(const f32x4*)(b_hh + HH + j);
  f32x4 bhn = *(const f32x4*)(b_hh + 2 * HH + j);
  u16x4 hob = *(const u16x4*)(h_old_bf + (size_t)b * HH + j);
  f32x4 fw  = *(const f32x4*)(fcw + j);
  float s = 0.f;
#pragma unroll
  for (int e = 0; e < 4; ++e) {
    float r = 1.f / (1.f + expf(-(bf2f(gir[e]) + bir[e] + bf2f(ghr[e]) + bhr[e])));
    float z = 1.f / (1.f + expf(-(bf2f(giz[e]) + biz[e] + bf2f(ghz[e]) + bhz[e])));
    float n = tanhf(bf2f(gin[e]) + bin[e] + r * (bf2f(ghn[e]) + bhn[e]));
    float h = (1.f - z) * n + z * bf2f(hob[e]);
    s += h * fw[e];
  }
#pragma unroll
  for (int off = 32; off > 0; off >>= 1) s += __shfl_down(s, off);
  __shared__ float red[4];
  if ((threadIdx.x & 63) == 0) red[threadIdx.x >> 6] = s;
  __syncthreads();
  if (threadIdx.x == 0) {
    float v = red[0] + red[1] + red[2] + red[3];
    if ((blockIdx.x & 3) == 0) v += fcb[0];
    atomicAdd(&out[b], v);
  }
}

extern "C" void kernel_launch(void* const* d_in, const int* in_sizes, int n_in,
                              void* d_out, int out_size, void* d_ws, size_t ws_size,
                              hipStream_t stream)
{
  const float* feat = (const float*)d_in[0];
  const float* Wih  = (const float*)d_in[1];
  const float* bih  = (const float*)d_in[2];
  const float* Whh  = (const float*)d_in[3];
  const float* bhh  = (const float*)d_in[4];
  const float* fcw  = (const float*)d_in[5];
  const float* fcb  = (const float*)d_in[6];
  float* out = (float*)d_out;

  char* ws = (char*)d_ws;
  unsigned short* Wc   = (unsigned short*)ws;                    // 201326592 B
  unsigned short* Cbuf = (unsigned short*)(ws + 201326592);      // 201326592 B
  unsigned short* hb   = (unsigned short*)(ws + 402653184);      //  33554432 B
  // total: 436207616 B

  hipMemsetAsync(out, 0, (size_t)out_size * sizeof(float), stream);
  prep<<<NB_W + NB_C, 256, 0, stream>>>(Wih, Whh, feat, Wc, hb);

  gemm_bt<<<GRID_GEMM, 512, 0, stream>>>(hb, Wc, Cbuf);
  gru1<<<16384, 256, 0, stream>>>(Cbuf, feat, bih, bhh, hb);

  gemm_bt<<<GRID_GEMM, 512, 0, stream>>>(hb, Wc, Cbuf);
  gru2_fc<<<16384, 256, 0, stream>>>(Cbuf, hb, bih, bhh, fcw, fcb, out);
}